// Round 1
// baseline (13437.309 us; speedup 1.0000x reference)
//
#include <hip/hip_runtime.h>

// Decoder: 2-layer LSTM (H=256) with scalar output feedback, T=512 steps,
// B=256 batch. One block per batch element, persistent over all steps.
// Weights pre-transposed (k-major) into d_ws for coalesced streaming from L2.

namespace {

constexpr int kB = 256;
constexpr int kT = 512;
constexpr int kH = 256;
constexpr int kG4 = 1024;  // 4*H gate rows

__device__ __forceinline__ float fsig(float v) { return 1.0f / (1.0f + __expf(-v)); }

// w: (1024, 256) row-major  ->  wt: (256, 1024)  (coalesced writes)
__global__ __launch_bounds__(1024) void transpose_w(const float* __restrict__ w,
                                                    float* __restrict__ wt) {
  unsigned idx = blockIdx.x * 1024u + threadIdx.x;  // 0 .. 262143
  unsigned j = idx & 1023u;                         // gate row
  unsigned k = idx >> 10;                           // input col
  wt[idx] = w[j * 256u + k];
}

template <bool USE_WT>
__global__ __launch_bounds__(1024) void decoder_rnn(
    const float* __restrict__ seq,   // (B,T,1)
    const float* __restrict__ z,     // (B,H)
    const float* __restrict__ wih0,  // (1024,1)
    const float* __restrict__ bih0, const float* __restrict__ bhh0,
    const float* __restrict__ whh0,  // (1024,256) row-major (fallback path)
    const float* __restrict__ wih1,  // (1024,256) row-major (fallback path)
    const float* __restrict__ whh1,  // (1024,256) row-major (fallback path)
    const float* __restrict__ bih1, const float* __restrict__ bhh1,
    const float* __restrict__ wout,  // (1,256)
    const float* __restrict__ bout,  // (1,)
    const float* __restrict__ wt_hh0,  // (256,1024) k-major
    const float* __restrict__ wt_ih1, const float* __restrict__ wt_hh1,
    float* __restrict__ loss_out) {
  __shared__ float h0s[kH];
  __shared__ float h1s[kH];
  __shared__ float g4[kG4];
  __shared__ float xs_s;

  const int tid = threadIdx.x;  // gate row j in [0,1024)
  const int b = blockIdx.x;     // batch element

  // init: h = c = z for both layers; pred0 = 0
  float c0r = 0.f, c1r = 0.f;
  if (tid < kH) {
    float zv = z[b * kH + tid];
    h0s[tid] = zv;
    h1s[tid] = zv;
    c0r = zv;
    c1r = zv;
  }
  if (tid == 0) xs_s = 0.f;

  const float wih0_j = wih0[tid];
  const float bias0_j = bih0[tid] + bhh0[tid];
  const float bias1_j = bih1[tid] + bhh1[tid];
  const float wout_r = (tid < kH) ? wout[tid] : 0.f;
  const float bo = bout[0];
  float lacc = 0.f;
  __syncthreads();

  for (int t = 0; t < kT; ++t) {
    // ---- layer 0: gates[j] = x*Wih0[j] + b + dot(Whh0[j,:], h0) ----
    float a0 = fmaf(xs_s, wih0_j, bias0_j);
    if (USE_WT) {
#pragma unroll 8
      for (int k = 0; k < kH; ++k) a0 = fmaf(wt_hh0[k * kG4 + tid], h0s[k], a0);
    } else {
#pragma unroll 8
      for (int k = 0; k < kH; ++k) a0 = fmaf(whh0[tid * kH + k], h0s[k], a0);
    }
    g4[tid] = a0;
    __syncthreads();
    if (tid < kH) {  // cell update for h-row tid (gate order i,f,g,o)
      float ig = fsig(g4[tid]);
      float fg = fsig(g4[tid + 256]);
      float gg = tanhf(g4[tid + 512]);
      float og = fsig(g4[tid + 768]);
      c0r = fmaf(fg, c0r, ig * gg);
      h0s[tid] = og * tanhf(c0r);
    }
    __syncthreads();

    // ---- layer 1: gates[j] = dot(Wih1[j,:], h0_new) + b + dot(Whh1[j,:], h1) ----
    float a1 = bias1_j;
    if (USE_WT) {
#pragma unroll 8
      for (int k = 0; k < kH; ++k) a1 = fmaf(wt_ih1[k * kG4 + tid], h0s[k], a1);
#pragma unroll 8
      for (int k = 0; k < kH; ++k) a1 = fmaf(wt_hh1[k * kG4 + tid], h1s[k], a1);
    } else {
#pragma unroll 8
      for (int k = 0; k < kH; ++k) a1 = fmaf(wih1[tid * kH + k], h0s[k], a1);
#pragma unroll 8
      for (int k = 0; k < kH; ++k) a1 = fmaf(whh1[tid * kH + k], h1s[k], a1);
    }
    g4[tid] = a1;
    __syncthreads();
    if (tid < kH) {
      float ig = fsig(g4[tid]);
      float fg = fsig(g4[tid + 256]);
      float gg = tanhf(g4[tid + 512]);
      float og = fsig(g4[tid + 768]);
      c1r = fmaf(fg, c1r, ig * gg);
      float h1 = og * tanhf(c1r);
      h1s[tid] = h1;
      g4[tid] = h1 * wout_r;  // pred partial (g4 gate values already consumed)
    }
    __syncthreads();

    // ---- pred = dot(h1, Wout) + b_out ; loss accum ; feedback ----
    if (tid < 64) {
      float v = g4[tid] + g4[tid + 64] + g4[tid + 128] + g4[tid + 192];
#pragma unroll
      for (int off = 32; off > 0; off >>= 1) v += __shfl_down(v, off);
      if (tid == 0) {
        float pred = v + bo;
        float d = seq[b * kT + t] - pred;
        lacc = fmaf(d, d, lacc);
        xs_s = pred;  // x input for step t+1
      }
    }
    __syncthreads();
  }

  if (tid == 0) atomicAdd(loss_out, lacc * (1.0f / (float)(kB * kT)));
}

}  // namespace

extern "C" void kernel_launch(void* const* d_in, const int* in_sizes, int n_in,
                              void* d_out, int out_size, void* d_ws, size_t ws_size,
                              hipStream_t stream) {
  const float* seq = (const float*)d_in[0];
  const float* z = (const float*)d_in[1];
  // d_in[2] = lengths (unused: reference runs full T and loss covers padded seq)
  const float* wih0 = (const float*)d_in[3];
  const float* whh0 = (const float*)d_in[4];
  const float* bih0 = (const float*)d_in[5];
  const float* bhh0 = (const float*)d_in[6];
  const float* wih1 = (const float*)d_in[7];
  const float* whh1 = (const float*)d_in[8];
  const float* bih1 = (const float*)d_in[9];
  const float* bhh1 = (const float*)d_in[10];
  const float* wout = (const float*)d_in[11];
  const float* bout = (const float*)d_in[12];
  float* out = (float*)d_out;

  hipMemsetAsync(out, 0, sizeof(float), stream);  // d_out re-poisoned each call

  const size_t mat = (size_t)kG4 * kH;  // 262144 elements per weight matrix
  const bool use_wt = ws_size >= 3 * mat * sizeof(float);

  if (use_wt) {
    float* wt0 = (float*)d_ws;
    float* wt1 = wt0 + mat;
    float* wt2 = wt1 + mat;
    transpose_w<<<256, 1024, 0, stream>>>(whh0, wt0);
    transpose_w<<<256, 1024, 0, stream>>>(wih1, wt1);
    transpose_w<<<256, 1024, 0, stream>>>(whh1, wt2);
    decoder_rnn<true><<<kB, 1024, 0, stream>>>(seq, z, wih0, bih0, bhh0, whh0,
                                               wih1, whh1, bih1, bhh1, wout, bout,
                                               wt0, wt1, wt2, out);
  } else {
    decoder_rnn<false><<<kB, 1024, 0, stream>>>(seq, z, wih0, bih0, bhh0, whh0,
                                                wih1, whh1, bih1, bhh1, wout, bout,
                                                nullptr, nullptr, nullptr, out);
  }
}